// Round 4
// baseline (917.474 us; speedup 1.0000x reference)
//
#include <hip/hip_runtime.h>
#include <hip/hip_bf16.h>

#define N_NODES 100000
#define N_RELS  4
#define N_EDGES 250000
#define TOTAL_E (N_RELS * N_EDGES)
#define NR      (N_RELS * N_NODES)
#define D       128

typedef __attribute__((ext_vector_type(8))) short bf16x8;
typedef __attribute__((ext_vector_type(4))) float f32x4;

__device__ __forceinline__ float b2f(short u) {
    unsigned int x = ((unsigned int)(unsigned short)u) << 16;
    return __builtin_bit_cast(float, x);
}
__device__ __forceinline__ unsigned short f2b(float f) {
    unsigned int u = __builtin_bit_cast(unsigned int, f);
    return (unsigned short)((u + 0x7fffu + ((u >> 16) & 1u)) >> 16);  // RNE
}

// ---------------------------------------------------------------------------
// prep: convert_x (blocks [0,6250)), convert_w ([6250,6570)), hist (rest).
// ---------------------------------------------------------------------------
#define PREP_X_BLKS 6250
#define PREP_W_BLKS 320
#define PREP_H_BLKS 3907
__global__ __launch_bounds__(256) void prep_kernel(
    const float* __restrict__ x, const float* __restrict__ weight,
    const float* __restrict__ loop_w, const int* __restrict__ dst,
    unsigned short* __restrict__ xb, unsigned short* __restrict__ wT,
    int* __restrict__ deg)
{
    int b = blockIdx.x, t = threadIdx.x;
    if (b < PREP_X_BLKS) {
        int i = b * 256 + t;                       // < 1,600,000 exactly
        float4 v0 = *reinterpret_cast<const float4*>(x + (size_t)i * 8);
        float4 v1 = *reinterpret_cast<const float4*>(x + (size_t)i * 8 + 4);
        bf16x8 o;
        o[0] = (short)f2b(v0.x); o[1] = (short)f2b(v0.y);
        o[2] = (short)f2b(v0.z); o[3] = (short)f2b(v0.w);
        o[4] = (short)f2b(v1.x); o[5] = (short)f2b(v1.y);
        o[6] = (short)f2b(v1.z); o[7] = (short)f2b(v1.w);
        *reinterpret_cast<bf16x8*>(xb + (size_t)i * 8) = o;
    } else if (b < PREP_X_BLKS + PREP_W_BLKS) {
        int i = (b - PREP_X_BLKS) * 256 + t;       // < 81920 exactly
        int mat = i >> 14;
        int n   = (i >> 7) & 127;
        int k   = i & 127;
        const float* srcm = (mat < 4) ? (weight + (size_t)mat * D * D) : loop_w;
        wT[i] = f2b(srcm[k * D + n]);
    } else {
        int i = (b - PREP_X_BLKS - PREP_W_BLKS) * 256 + t;
        if (i < TOTAL_E) {
            int rel = i / N_EDGES;
            atomicAdd(&deg[rel * N_NODES + dst[i]], 1);
        }
    }
}

// ---------------------------------------------------------------------------
// scan1: per-1024-chunk exclusive scan, chunk totals -> aux
// ---------------------------------------------------------------------------
__global__ __launch_bounds__(256) void scan1_kernel(
    const int* __restrict__ in, int* __restrict__ out,
    int* __restrict__ aux, int n)
{
    __shared__ int s[256];
    int t = threadIdx.x;
    int base = blockIdx.x * 1024 + t * 4;
    int v[4];
    int sum = 0;
    #pragma unroll
    for (int j = 0; j < 4; ++j) {
        v[j] = (base + j < n) ? in[base + j] : 0;
        sum += v[j];
    }
    s[t] = sum;
    for (int off = 1; off < 256; off <<= 1) {
        __syncthreads();
        int u = (t >= off) ? s[t - off] : 0;
        __syncthreads();
        s[t] += u;
    }
    __syncthreads();
    int excl = (t > 0) ? s[t - 1] : 0;
    #pragma unroll
    for (int j = 0; j < 4; ++j) {
        if (base + j < n) out[base + j] = excl;
        excl += v[j];
    }
    if (t == 255) aux[blockIdx.x] = s[255];
}

// ---------------------------------------------------------------------------
// addoff2: each block reduces aux[0..chunk) itself (inline scan2), then
// adds the prefix to its 1024 off entries and mirrors into cursor.
// ---------------------------------------------------------------------------
__global__ __launch_bounds__(256) void addoff2_kernel(
    int* __restrict__ off, int* __restrict__ cursor,
    const int* __restrict__ aux, int n)
{
    __shared__ int sred[256];
    int c = blockIdx.x, t = threadIdx.x;
    int part = 0;
    for (int j = t; j < c; j += 256) part += aux[j];
    sred[t] = part;
    for (int o = 128; o > 0; o >>= 1) {
        __syncthreads();
        if (t < o) sred[t] += sred[t + o];
    }
    __syncthreads();
    int S = sred[0];
    int base = c * 1024 + t * 4;
    #pragma unroll
    for (int j = 0; j < 4; ++j) {
        int i = base + j;
        if (i < n) { int v = off[i] + S; off[i] = v; cursor[i] = v; }
    }
}

// ---------------------------------------------------------------------------
// fill: sorted_pack[pos] = src | ((dst & 31) << 17)  (block-local row in hi)
// ---------------------------------------------------------------------------
__global__ __launch_bounds__(256) void fill_pack_kernel(
    const int* __restrict__ dst, const int* __restrict__ src,
    int* __restrict__ cursor, unsigned int* __restrict__ sorted_pack, int total)
{
    int i = blockIdx.x * 256 + threadIdx.x;
    if (i >= total) return;
    int rel = i / N_EDGES;
    int d = dst[i];
    int pos = atomicAdd(&cursor[rel * N_NODES + d], 1);
    sorted_pack[pos] = (unsigned int)src[i] | ((unsigned int)(d & 31) << 17);
}

// ---------------------------------------------------------------------------
// Fused MFMA kernel, 32-row tile, 256 threads (4 waves x 32 cols).
// Per relation phase: zero f32 LDS tile -> edge-parallel gather with
// ds_add_f32 (16 lanes/edge) -> normalize + bf16-convert into swizzled sIn
// -> MFMA. Self-loop phase reads A-frags straight from global xb.
// ---------------------------------------------------------------------------
__global__ __launch_bounds__(256) void fused_gemm_mfma(
    const unsigned short* __restrict__ xb,   // [N,128] bf16
    const unsigned short* __restrict__ wT,   // [5,128,128] bf16 n-major
    const float* __restrict__ conv_bias,     // [4,128]
    const float* __restrict__ node_bias,     // [128]
    const int* __restrict__ deg,             // [4*N]
    const int* __restrict__ off,             // [4*N]
    const unsigned int* __restrict__ spack,  // [1M]
    float* __restrict__ out)                 // [N,128] f32
{
    __shared__ float tileF[32 * 128];                       // 16 KB, swizzled
    __shared__ __align__(16) unsigned char sIn[32 * 256];   // 8 KB, swizzled

    const int tid  = threadIdx.x;
    const int row0 = blockIdx.x * 32;
    const int wid  = tid >> 6;
    const int lane = tid & 63;
    const int l15  = lane & 15;
    const int l4   = lane >> 4;
    const int swA  = (l15 & 7) << 4;

    // gather mapping: 16 lanes per edge, 4 edges per wave
    const int glc = lane & 15;     // 16B chunk within row
    const int gew = lane >> 4;     // edge slot within wave

    // normalize mapping: thread -> (row, 16-col chunk)
    const int nr = tid >> 3;           // row 0..31
    const int nc = (tid & 7) * 16;     // col base
    const int nsw = (nr & 7) << 4;

    f32x4 acc_mean[2][2];
    f32x4 acc_self[2][2];
    #pragma unroll
    for (int m = 0; m < 2; ++m)
        #pragma unroll
        for (int n = 0; n < 2; ++n)
            acc_mean[m][n] = (f32x4){0.f, 0.f, 0.f, 0.f};

    for (int phase = 0; phase < 4; ++phase) {
        // ---- zero f32 tile (16 floats/thread) ----
        __syncthreads();   // prev phase: tileF reads + sIn frag reads done
        #pragma unroll
        for (int k = 0; k < 4; ++k)
            *reinterpret_cast<f32x4*>(&tileF[tid * 16 + k * 4]) =
                (f32x4){0.f, 0.f, 0.f, 0.f};
        __syncthreads();

        // ---- edge-parallel gather: ds_add_f32 into swizzled tileF ----
        {
            int ebeg = off[phase * N_NODES + row0];
            int eidx = phase * N_NODES + row0 + 32;
            int eend = (eidx < NR) ? off[eidx] : TOTAL_E;
            for (int e = ebeg + wid * 4 + gew; e < eend; e += 16) {
                unsigned int pk = spack[e];
                int srcn = pk & 0x1FFFF;
                int lrow = (pk >> 17) & 31;
                bf16x8 v = *reinterpret_cast<const bf16x8*>(
                    xb + (size_t)srcn * D + glc * 8);
                char* base = (char*)tileF + lrow * 512;
                int sw = (lrow & 7) << 4;
                #pragma unroll
                for (int j = 0; j < 8; ++j) {
                    int boff = (glc * 32 + j * 4) ^ sw;
                    atomicAdd(reinterpret_cast<float*>(base + boff), b2f(v[j]));
                }
            }
        }
        __syncthreads();

        // ---- normalize + convert into swizzled bf16 sIn ----
        {
            int dg = deg[phase * N_NODES + row0 + nr];
            float scl = 1.0f / fmaxf((float)dg, 1.0f);
            float vals[16];
            #pragma unroll
            for (int k = 0; k < 4; ++k) {
                f32x4 q = *reinterpret_cast<const f32x4*>(
                    (char*)tileF + nr * 512 + (((tid & 7) * 64 + k * 16) ^ nsw));
                vals[k * 4 + 0] = q.x * scl; vals[k * 4 + 1] = q.y * scl;
                vals[k * 4 + 2] = q.z * scl; vals[k * 4 + 3] = q.w * scl;
            }
            #pragma unroll
            for (int k = 0; k < 2; ++k) {
                bf16x8 o;
                #pragma unroll
                for (int j = 0; j < 8; ++j)
                    o[j] = (short)f2b(vals[k * 8 + j]);
                *reinterpret_cast<bf16x8*>(
                    &sIn[nr * 256 + (((tid & 7) * 32 + k * 16) ^ nsw)]) = o;
            }
        }
        __syncthreads();

        // ---- MFMA: A from sIn, B from global wT (L2-resident) ----
        const unsigned short* wp = wT + (size_t)phase * D * D;
        f32x4 acc[2][2];
        #pragma unroll
        for (int m = 0; m < 2; ++m)
            #pragma unroll
            for (int n = 0; n < 2; ++n)
                acc[m][n] = (f32x4){0.f, 0.f, 0.f, 0.f};

        #pragma unroll
        for (int s = 0; s < 4; ++s) {
            int kb = s * 64 + l4 * 16;
            bf16x8 a0 = *reinterpret_cast<const bf16x8*>(
                &sIn[l15 * 256 + (kb ^ swA)]);
            bf16x8 a1 = *reinterpret_cast<const bf16x8*>(
                &sIn[(16 + l15) * 256 + (kb ^ swA)]);
            bf16x8 b0 = *reinterpret_cast<const bf16x8*>(
                wp + (wid * 32 + l15) * D + s * 32 + l4 * 8);
            bf16x8 b1 = *reinterpret_cast<const bf16x8*>(
                wp + (wid * 32 + 16 + l15) * D + s * 32 + l4 * 8);
            acc[0][0] = __builtin_amdgcn_mfma_f32_16x16x32_bf16(a0, b0, acc[0][0], 0, 0, 0);
            acc[0][1] = __builtin_amdgcn_mfma_f32_16x16x32_bf16(a0, b1, acc[0][1], 0, 0, 0);
            acc[1][0] = __builtin_amdgcn_mfma_f32_16x16x32_bf16(a1, b0, acc[1][0], 0, 0, 0);
            acc[1][1] = __builtin_amdgcn_mfma_f32_16x16x32_bf16(a1, b1, acc[1][1], 0, 0, 0);
        }

        float b0 = conv_bias[phase * D + wid * 32 + l15];
        float b1 = conv_bias[phase * D + wid * 32 + 16 + l15];
        #pragma unroll
        for (int m = 0; m < 2; ++m)
            #pragma unroll
            for (int j = 0; j < 4; ++j) {
                acc_mean[m][0][j] += 0.25f * fmaxf(acc[m][0][j] + b0, 0.f);
                acc_mean[m][1][j] += 0.25f * fmaxf(acc[m][1][j] + b1, 0.f);
            }
    }

    // ---- self-loop phase: A-frags direct from global xb ----
    {
        const unsigned short* wp = wT + (size_t)4 * D * D;
        f32x4 acc[2][2];
        #pragma unroll
        for (int m = 0; m < 2; ++m)
            #pragma unroll
            for (int n = 0; n < 2; ++n)
                acc[m][n] = (f32x4){0.f, 0.f, 0.f, 0.f};

        #pragma unroll
        for (int s = 0; s < 4; ++s) {
            bf16x8 a0 = *reinterpret_cast<const bf16x8*>(
                xb + (size_t)(row0 + l15) * D + s * 32 + l4 * 8);
            bf16x8 a1 = *reinterpret_cast<const bf16x8*>(
                xb + (size_t)(row0 + 16 + l15) * D + s * 32 + l4 * 8);
            bf16x8 b0 = *reinterpret_cast<const bf16x8*>(
                wp + (wid * 32 + l15) * D + s * 32 + l4 * 8);
            bf16x8 b1 = *reinterpret_cast<const bf16x8*>(
                wp + (wid * 32 + 16 + l15) * D + s * 32 + l4 * 8);
            acc[0][0] = __builtin_amdgcn_mfma_f32_16x16x32_bf16(a0, b0, acc[0][0], 0, 0, 0);
            acc[0][1] = __builtin_amdgcn_mfma_f32_16x16x32_bf16(a0, b1, acc[0][1], 0, 0, 0);
            acc[1][0] = __builtin_amdgcn_mfma_f32_16x16x32_bf16(a1, b0, acc[1][0], 0, 0, 0);
            acc[1][1] = __builtin_amdgcn_mfma_f32_16x16x32_bf16(a1, b1, acc[1][1], 0, 0, 0);
        }
        float b0 = node_bias[wid * 32 + l15];
        float b1 = node_bias[wid * 32 + 16 + l15];
        #pragma unroll
        for (int m = 0; m < 2; ++m)
            #pragma unroll
            for (int j = 0; j < 4; ++j) {
                acc_self[m][0][j] = acc[m][0][j] + b0;
                acc_self[m][1][j] = acc[m][1][j] + b1;
            }
    }

    // ---- final epilogue: relu(silu(mean) + self) ----
    #pragma unroll
    for (int m = 0; m < 2; ++m)
        #pragma unroll
        for (int n = 0; n < 2; ++n)
            #pragma unroll
            for (int j = 0; j < 4; ++j) {
                float mn = acc_mean[m][n][j];                // >= 0
                float sl = mn / (1.0f + __expf(-mn));
                float v  = fmaxf(sl + acc_self[m][n][j], 0.f);
                int row = row0 + m * 16 + l4 * 4 + j;
                int col = wid * 32 + n * 16 + l15;
                out[(size_t)row * D + col] = v;
            }
}

// ---------------------------------------------------------------------------
extern "C" void kernel_launch(void* const* d_in, const int* in_sizes, int n_in,
                              void* d_out, int out_size, void* d_ws, size_t ws_size,
                              hipStream_t stream) {
    const float* x         = (const float*)d_in[0];
    const float* weight    = (const float*)d_in[1];
    const float* conv_bias = (const float*)d_in[2];
    const float* loop_w    = (const float*)d_in[3];
    const float* node_bias = (const float*)d_in[4];
    const int*   src       = (const int*)d_in[5];
    const int*   dst       = (const int*)d_in[6];
    float* out = (float*)d_out;

    // ws layout (bytes)
    char* w = (char*)d_ws;
    int* deg                  = (int*)(w);                    // 1.6 MB
    int* off                  = (int*)(w + 1600000);          // 1.6 MB
    int* cursor               = (int*)(w + 3200000);          // 1.6 MB
    int* aux                  = (int*)(w + 4800000);          // 2 KB
    unsigned int* spack       = (unsigned int*)(w + 4802048); // 4 MB
    unsigned short* xb        = (unsigned short*)(w + 8802048);   // 25.6 MB
    unsigned short* wT        = (unsigned short*)(w + 8802048 + (size_t)N_NODES * D * 2);

    const int SCAN_BLKS = (NR + 1023) / 1024;   // 391

    hipMemsetAsync(deg, 0, NR * sizeof(int), stream);
    prep_kernel<<<PREP_X_BLKS + PREP_W_BLKS + PREP_H_BLKS, 256, 0, stream>>>(
        x, weight, loop_w, dst, xb, wT, deg);
    scan1_kernel<<<SCAN_BLKS, 256, 0, stream>>>(deg, off, aux, NR);
    addoff2_kernel<<<SCAN_BLKS, 256, 0, stream>>>(off, cursor, aux, NR);
    fill_pack_kernel<<<(TOTAL_E + 255) / 256, 256, 0, stream>>>(
        dst, src, cursor, spack, TOTAL_E);
    fused_gemm_mfma<<<N_NODES / 32, 256, 0, stream>>>(
        xb, wT, conv_bias, node_bias, deg, off, spack, out);
}

// Round 5
// 356.941 us; speedup vs baseline: 2.5704x; 2.5704x over previous
//
#include <hip/hip_runtime.h>
#include <hip/hip_bf16.h>

#define N_NODES 100000
#define N_RELS  4
#define N_EDGES 250000
#define TOTAL_E (N_RELS * N_EDGES)
#define NR      (N_RELS * N_NODES)
#define D       128

typedef __attribute__((ext_vector_type(8))) short bf16x8;
typedef __attribute__((ext_vector_type(4))) float f32x4;

__device__ __forceinline__ float b2f(short u) {
    unsigned int x = ((unsigned int)(unsigned short)u) << 16;
    return __builtin_bit_cast(float, x);
}
__device__ __forceinline__ unsigned short f2b(float f) {
    unsigned int u = __builtin_bit_cast(unsigned int, f);
    return (unsigned short)((u + 0x7fffu + ((u >> 16) & 1u)) >> 16);  // RNE
}

// ---------------------------------------------------------------------------
// prep: convert_x (blocks [0,6250)), convert_w ([6250,6570)), hist (rest).
// ---------------------------------------------------------------------------
#define PREP_X_BLKS 6250
#define PREP_W_BLKS 320
#define PREP_H_BLKS 3907
__global__ __launch_bounds__(256) void prep_kernel(
    const float* __restrict__ x, const float* __restrict__ weight,
    const float* __restrict__ loop_w, const int* __restrict__ dst,
    unsigned short* __restrict__ xb, unsigned short* __restrict__ wT,
    int* __restrict__ deg)
{
    int b = blockIdx.x, t = threadIdx.x;
    if (b < PREP_X_BLKS) {
        int i = b * 256 + t;                       // < 1,600,000 exactly
        float4 v0 = *reinterpret_cast<const float4*>(x + (size_t)i * 8);
        float4 v1 = *reinterpret_cast<const float4*>(x + (size_t)i * 8 + 4);
        bf16x8 o;
        o[0] = (short)f2b(v0.x); o[1] = (short)f2b(v0.y);
        o[2] = (short)f2b(v0.z); o[3] = (short)f2b(v0.w);
        o[4] = (short)f2b(v1.x); o[5] = (short)f2b(v1.y);
        o[6] = (short)f2b(v1.z); o[7] = (short)f2b(v1.w);
        *reinterpret_cast<bf16x8*>(xb + (size_t)i * 8) = o;
    } else if (b < PREP_X_BLKS + PREP_W_BLKS) {
        int i = (b - PREP_X_BLKS) * 256 + t;       // < 81920 exactly
        int mat = i >> 14;
        int n   = (i >> 7) & 127;
        int k   = i & 127;
        const float* srcm = (mat < 4) ? (weight + (size_t)mat * D * D) : loop_w;
        wT[i] = f2b(srcm[k * D + n]);
    } else {
        int i = (b - PREP_X_BLKS - PREP_W_BLKS) * 256 + t;
        if (i < TOTAL_E) {
            int rel = i / N_EDGES;
            atomicAdd(&deg[rel * N_NODES + dst[i]], 1);
        }
    }
}

// ---------------------------------------------------------------------------
// scan1: per-1024-chunk exclusive scan, chunk totals -> aux
// ---------------------------------------------------------------------------
__global__ __launch_bounds__(256) void scan1_kernel(
    const int* __restrict__ in, int* __restrict__ out,
    int* __restrict__ aux, int n)
{
    __shared__ int s[256];
    int t = threadIdx.x;
    int base = blockIdx.x * 1024 + t * 4;
    int v[4];
    int sum = 0;
    #pragma unroll
    for (int j = 0; j < 4; ++j) {
        v[j] = (base + j < n) ? in[base + j] : 0;
        sum += v[j];
    }
    s[t] = sum;
    for (int off = 1; off < 256; off <<= 1) {
        __syncthreads();
        int u = (t >= off) ? s[t - off] : 0;
        __syncthreads();
        s[t] += u;
    }
    __syncthreads();
    int excl = (t > 0) ? s[t - 1] : 0;
    #pragma unroll
    for (int j = 0; j < 4; ++j) {
        if (base + j < n) out[base + j] = excl;
        excl += v[j];
    }
    if (t == 255) aux[blockIdx.x] = s[255];
}

// ---------------------------------------------------------------------------
// addoff2: inline scan of aux + add prefix; mirrors into cursor; writes
// the off[NR] sentinel so deg can be derived as off[i+1]-off[i].
// ---------------------------------------------------------------------------
__global__ __launch_bounds__(256) void addoff2_kernel(
    int* __restrict__ off, int* __restrict__ cursor,
    const int* __restrict__ aux, int n)
{
    __shared__ int sred[256];
    int c = blockIdx.x, t = threadIdx.x;
    if (c == 0 && t == 0) off[NR] = TOTAL_E;   // sentinel
    int part = 0;
    for (int j = t; j < c; j += 256) part += aux[j];
    sred[t] = part;
    for (int o = 128; o > 0; o >>= 1) {
        __syncthreads();
        if (t < o) sred[t] += sred[t + o];
    }
    __syncthreads();
    int S = sred[0];
    int base = c * 1024 + t * 4;
    #pragma unroll
    for (int j = 0; j < 4; ++j) {
        int i = base + j;
        if (i < n) { int v = off[i] + S; off[i] = v; cursor[i] = v; }
    }
}

// ---------------------------------------------------------------------------
// fill: sorted_src[pos] = src  (edges grouped per (rel,dst), CSR order)
// ---------------------------------------------------------------------------
__global__ __launch_bounds__(256) void fill_kernel(
    const int* __restrict__ dst, const int* __restrict__ src,
    int* __restrict__ cursor, int* __restrict__ sorted_src, int total)
{
    int i = blockIdx.x * 256 + threadIdx.x;
    if (i >= total) return;
    int rel = i / N_EDGES;
    int pos = atomicAdd(&cursor[rel * N_NODES + dst[i]], 1);
    sorted_src[pos] = src[i];
}

// ---------------------------------------------------------------------------
// Fused MFMA kernel, 32-row tile, 256 threads (4 waves x 32 output cols).
// Per relation phase: register-accumulating CSR gather (8 threads/row,
// 16 cols each, edge loop UNROLLED x4 for MLP) -> normalize -> bf16 ->
// swizzled LDS A-tile -> MFMA (B frags direct from L2-resident wT).
// Self-loop phase: A-frags straight from global xb. One output write.
// ---------------------------------------------------------------------------
__global__ __launch_bounds__(256) void fused_gemm_mfma(
    const unsigned short* __restrict__ xb,   // [N,128] bf16
    const unsigned short* __restrict__ wT,   // [5,128,128] bf16 n-major
    const float* __restrict__ conv_bias,     // [4,128]
    const float* __restrict__ node_bias,     // [128]
    const int* __restrict__ off,             // [4*N + 1] (sentinel)
    const int* __restrict__ sorted_src,      // [1M]
    float* __restrict__ out)                 // [N,128] f32
{
    __shared__ __align__(16) unsigned char sIn[32 * 256];   // 8 KB, swizzled

    const int tid  = threadIdx.x;
    const int row0 = blockIdx.x * 32;
    const int wid  = tid >> 6;
    const int lane = tid & 63;
    const int l15  = lane & 15;
    const int l4   = lane >> 4;
    const int swA  = (l15 & 7) << 4;

    // gather mapping: 8 threads/row, 16 cols (32 B) each
    const int gr  = tid >> 3;
    const int gc  = tid & 7;
    const int gsw = (gr & 7) << 4;

    f32x4 acc_mean[2][2];
    f32x4 acc_self[2][2];
    #pragma unroll
    for (int m = 0; m < 2; ++m)
        #pragma unroll
        for (int n = 0; n < 2; ++n)
            acc_mean[m][n] = (f32x4){0.f, 0.f, 0.f, 0.f};

    for (int phase = 0; phase < 4; ++phase) {
        __syncthreads();   // previous phase's sIn frag reads done

        // ---- CSR gather, unrolled x4 for memory-level parallelism ----
        {
            int node = phase * N_NODES + row0 + gr;
            int beg  = off[node];
            int dgi  = off[node + 1] - beg;
            const int* sp = sorted_src + beg;
            const unsigned short* xcol = xb + gc * 16;

            float a[16];
            #pragma unroll
            for (int j = 0; j < 16; ++j) a[j] = 0.f;

            int e = 0;
            for (; e + 4 <= dgi; e += 4) {
                int s0 = sp[e], s1 = sp[e + 1], s2 = sp[e + 2], s3 = sp[e + 3];
                const bf16x8* p0 = reinterpret_cast<const bf16x8*>(xcol + (size_t)s0 * D);
                const bf16x8* p1 = reinterpret_cast<const bf16x8*>(xcol + (size_t)s1 * D);
                const bf16x8* p2 = reinterpret_cast<const bf16x8*>(xcol + (size_t)s2 * D);
                const bf16x8* p3 = reinterpret_cast<const bf16x8*>(xcol + (size_t)s3 * D);
                bf16x8 u0 = p0[0], w0 = p0[1];
                bf16x8 u1 = p1[0], w1 = p1[1];
                bf16x8 u2 = p2[0], w2 = p2[1];
                bf16x8 u3 = p3[0], w3 = p3[1];
                #pragma unroll
                for (int j = 0; j < 8; ++j) {
                    a[j]     += b2f(u0[j]) + b2f(u1[j]) + b2f(u2[j]) + b2f(u3[j]);
                    a[8 + j] += b2f(w0[j]) + b2f(w1[j]) + b2f(w2[j]) + b2f(w3[j]);
                }
            }
            for (; e < dgi; ++e) {
                const bf16x8* p = reinterpret_cast<const bf16x8*>(xcol + (size_t)sp[e] * D);
                bf16x8 u = p[0], w = p[1];
                #pragma unroll
                for (int j = 0; j < 8; ++j) {
                    a[j]     += b2f(u[j]);
                    a[8 + j] += b2f(w[j]);
                }
            }

            float scl = 1.0f / fmaxf((float)dgi, 1.0f);
            bf16x8 o0, o1;
            #pragma unroll
            for (int j = 0; j < 8; ++j) {
                o0[j] = (short)f2b(a[j] * scl);
                o1[j] = (short)f2b(a[8 + j] * scl);
            }
            int base = gr * 256;
            *reinterpret_cast<bf16x8*>(&sIn[base + ((gc * 32) ^ gsw)])      = o0;
            *reinterpret_cast<bf16x8*>(&sIn[base + ((gc * 32 + 16) ^ gsw)]) = o1;
        }
        __syncthreads();

        // ---- MFMA: A from sIn, B from global wT (L2-resident) ----
        const unsigned short* wp = wT + (size_t)phase * D * D;
        f32x4 acc[2][2];
        #pragma unroll
        for (int m = 0; m < 2; ++m)
            #pragma unroll
            for (int n = 0; n < 2; ++n)
                acc[m][n] = (f32x4){0.f, 0.f, 0.f, 0.f};

        #pragma unroll
        for (int s = 0; s < 4; ++s) {
            int kb = s * 64 + l4 * 16;
            bf16x8 a0 = *reinterpret_cast<const bf16x8*>(
                &sIn[l15 * 256 + (kb ^ swA)]);
            bf16x8 a1 = *reinterpret_cast<const bf16x8*>(
                &sIn[(16 + l15) * 256 + (kb ^ swA)]);
            bf16x8 b0 = *reinterpret_cast<const bf16x8*>(
                wp + (wid * 32 + l15) * D + s * 32 + l4 * 8);
            bf16x8 b1 = *reinterpret_cast<const bf16x8*>(
                wp + (wid * 32 + 16 + l15) * D + s * 32 + l4 * 8);
            acc[0][0] = __builtin_amdgcn_mfma_f32_16x16x32_bf16(a0, b0, acc[0][0], 0, 0, 0);
            acc[0][1] = __builtin_amdgcn_mfma_f32_16x16x32_bf16(a0, b1, acc[0][1], 0, 0, 0);
            acc[1][0] = __builtin_amdgcn_mfma_f32_16x16x32_bf16(a1, b0, acc[1][0], 0, 0, 0);
            acc[1][1] = __builtin_amdgcn_mfma_f32_16x16x32_bf16(a1, b1, acc[1][1], 0, 0, 0);
        }

        float b0 = conv_bias[phase * D + wid * 32 + l15];
        float b1 = conv_bias[phase * D + wid * 32 + 16 + l15];
        #pragma unroll
        for (int m = 0; m < 2; ++m)
            #pragma unroll
            for (int j = 0; j < 4; ++j) {
                acc_mean[m][0][j] += 0.25f * fmaxf(acc[m][0][j] + b0, 0.f);
                acc_mean[m][1][j] += 0.25f * fmaxf(acc[m][1][j] + b1, 0.f);
            }
    }

    // ---- self-loop phase: A-frags direct from global xb ----
    {
        const unsigned short* wp = wT + (size_t)4 * D * D;
        f32x4 acc[2][2];
        #pragma unroll
        for (int m = 0; m < 2; ++m)
            #pragma unroll
            for (int n = 0; n < 2; ++n)
                acc[m][n] = (f32x4){0.f, 0.f, 0.f, 0.f};

        #pragma unroll
        for (int s = 0; s < 4; ++s) {
            bf16x8 a0 = *reinterpret_cast<const bf16x8*>(
                xb + (size_t)(row0 + l15) * D + s * 32 + l4 * 8);
            bf16x8 a1 = *reinterpret_cast<const bf16x8*>(
                xb + (size_t)(row0 + 16 + l15) * D + s * 32 + l4 * 8);
            bf16x8 b0 = *reinterpret_cast<const bf16x8*>(
                wp + (wid * 32 + l15) * D + s * 32 + l4 * 8);
            bf16x8 b1 = *reinterpret_cast<const bf16x8*>(
                wp + (wid * 32 + 16 + l15) * D + s * 32 + l4 * 8);
            acc[0][0] = __builtin_amdgcn_mfma_f32_16x16x32_bf16(a0, b0, acc[0][0], 0, 0, 0);
            acc[0][1] = __builtin_amdgcn_mfma_f32_16x16x32_bf16(a0, b1, acc[0][1], 0, 0, 0);
            acc[1][0] = __builtin_amdgcn_mfma_f32_16x16x32_bf16(a1, b0, acc[1][0], 0, 0, 0);
            acc[1][1] = __builtin_amdgcn_mfma_f32_16x16x32_bf16(a1, b1, acc[1][1], 0, 0, 0);
        }
        float b0 = node_bias[wid * 32 + l15];
        float b1 = node_bias[wid * 32 + 16 + l15];
        #pragma unroll
        for (int m = 0; m < 2; ++m)
            #pragma unroll
            for (int j = 0; j < 4; ++j) {
                acc_self[m][0][j] = acc[m][0][j] + b0;
                acc_self[m][1][j] = acc[m][1][j] + b1;
            }
    }

    // ---- final epilogue: relu(silu(mean) + self) ----
    #pragma unroll
    for (int m = 0; m < 2; ++m)
        #pragma unroll
        for (int n = 0; n < 2; ++n)
            #pragma unroll
            for (int j = 0; j < 4; ++j) {
                float mn = acc_mean[m][n][j];                // >= 0
                float sl = mn / (1.0f + __expf(-mn));
                float v  = fmaxf(sl + acc_self[m][n][j], 0.f);
                int row = row0 + m * 16 + l4 * 4 + j;
                int col = wid * 32 + n * 16 + l15;
                out[(size_t)row * D + col] = v;
            }
}

// ---------------------------------------------------------------------------
extern "C" void kernel_launch(void* const* d_in, const int* in_sizes, int n_in,
                              void* d_out, int out_size, void* d_ws, size_t ws_size,
                              hipStream_t stream) {
    const float* x         = (const float*)d_in[0];
    const float* weight    = (const float*)d_in[1];
    const float* conv_bias = (const float*)d_in[2];
    const float* loop_w    = (const float*)d_in[3];
    const float* node_bias = (const float*)d_in[4];
    const int*   src       = (const int*)d_in[5];
    const int*   dst       = (const int*)d_in[6];
    float* out = (float*)d_out;

    // ws layout (bytes)
    char* w = (char*)d_ws;
    int* deg            = (int*)(w);                      // 1.6 MB
    int* off            = (int*)(w + 1600000);            // 1.6 MB + sentinel
    int* cursor         = (int*)(w + 3200008);            // 1.6 MB
    int* aux            = (int*)(w + 4800008);            // 2 KB
    int* sorted_src     = (int*)(w + 4802056);            // 4 MB
    unsigned short* xb  = (unsigned short*)(w + 8802056); // 25.6 MB
    unsigned short* wT  = (unsigned short*)(w + 8802056 + (size_t)N_NODES * D * 2);

    const int SCAN_BLKS = (NR + 1023) / 1024;   // 391

    hipMemsetAsync(deg, 0, NR * sizeof(int), stream);
    prep_kernel<<<PREP_X_BLKS + PREP_W_BLKS + PREP_H_BLKS, 256, 0, stream>>>(
        x, weight, loop_w, dst, xb, wT, deg);
    scan1_kernel<<<SCAN_BLKS, 256, 0, stream>>>(deg, off, aux, NR);
    addoff2_kernel<<<SCAN_BLKS, 256, 0, stream>>>(off, cursor, aux, NR);
    fill_kernel<<<(TOTAL_E + 255) / 256, 256, 0, stream>>>(
        dst, src, cursor, sorted_src, TOTAL_E);
    fused_gemm_mfma<<<N_NODES / 32, 256, 0, stream>>>(
        xb, wT, conv_bias, node_bias, off, sorted_src, out);
}